// Round 5
// baseline (3730.369 us; speedup 1.0000x reference)
//
#include <hip/hip_runtime.h>

#define Hdim 200
#define NP   800
#define Tlen 100
#define BT   32          // batch rows per WG -> grid = 256 = 1 WG/CU
#define KB   7           // K blocks of 32 (200 -> 224 padded)
#define HS   232         // padded h row stride (ushorts)
#define NT   50          // 800/16 gate-col tiles
#define THREADS 640      // 10 waves x 5 M-tiles each
#define CH   5           // M-tiles per wave
#define CHSTR (NT*64*8)  // ushorts per K-chunk (25600)
#define MATSZ (KB*CHSTR) // 179200 ushorts per packed matrix
#define SBUF  2560       // ushorts per (ballast) stage buffer

// s_waitcnt immediates: vm[3:0]|exp[6:4]|lgkm[11:8]|vm[15:14]
#define WAIT_LGKM0 0xC07F   // lgkmcnt(0)

typedef float f32x4 __attribute__((ext_vector_type(4)));
typedef short s16x8 __attribute__((ext_vector_type(8)));

__device__ __forceinline__ ushort f2bf(float f) {
    unsigned u = __float_as_uint(f);
    return (ushort)((u + 0x7fffu + ((u >> 16) & 1u)) >> 16);   // RTNE
}
__device__ __forceinline__ float bf2f(ushort s) {
    return __uint_as_float(((unsigned)s) << 16);
}
__device__ __forceinline__ float sigmoid_fast(float v) {
    return 1.0f / (1.0f + __expf(-v));
}
__device__ __forceinline__ float tanh_fast(float v) {
    return 2.0f / (1.0f + __expf(-2.0f * v)) - 1.0f;
}
// WG barrier WITHOUT vmcnt drain: LDS visibility needs lgkmcnt(0) only.
// Weight prefetch loads in flight target wave-private REGISTERS -> safe across barrier.
__device__ __forceinline__ void wg_barrier() {
    asm volatile("" ::: "memory");
    __builtin_amdgcn_s_waitcnt(WAIT_LGKM0);
    __builtin_amdgcn_s_barrier();
    asm volatile("" ::: "memory");
}

// ---- pack 5 recurrent matrices [200][800] fp32 -> bf16 fragment layout ----
// order in d_ws: [U0, W1, U1, W2, U2]
__global__ void pack_weights(const float* __restrict__ U0, const float* __restrict__ W1,
                             const float* __restrict__ U1, const float* __restrict__ W2,
                             const float* __restrict__ U2, ushort* __restrict__ dst) {
    int idx = blockIdx.x * blockDim.x + threadIdx.x;
    if (idx >= 5 * KB * NT * 64) return;
    int lane = idx & 63; int rest = idx >> 6;
    int nt = rest % NT; rest /= NT;
    int kb = rest % KB; int mi = rest / KB;
    const float* src = (mi == 0) ? U0 : (mi == 1) ? W1 : (mi == 2) ? U1 : (mi == 3) ? W2 : U2;
    int np = nt * 16 + (lane & 15);
    int ncol = (np & 3) * Hdim + (np >> 2);          // gate*200 + unit
    int k0 = kb * 32 + (lane >> 4) * 8;
    ushort v[8];
#pragma unroll
    for (int j = 0; j < 8; ++j) {
        int k = k0 + j;
        v[j] = (k < Hdim) ? f2bf(src[k * NP + ncol]) : (ushort)0;
    }
    uint4 o;
    o.x = (unsigned)v[0] | ((unsigned)v[1] << 16);
    o.y = (unsigned)v[2] | ((unsigned)v[3] << 16);
    o.z = (unsigned)v[4] | ((unsigned)v[5] << 16);
    o.w = (unsigned)v[6] | ((unsigned)v[7] << 16);
    ((uint4*)dst)[idx] = o;
}

__device__ __forceinline__ void unpack4(const ushort* p, float (&o)[4]) {
    uint2 u = *(const uint2*)p;
    o[0] = bf2f((ushort)(u.x));  o[1] = bf2f((ushort)(u.x >> 16));
    o[2] = bf2f((ushort)(u.y));  o[3] = bf2f((ushort)(u.y >> 16));
}

// lane-local cell update (unchanged)
__device__ __forceinline__ void gate_phase(f32x4 (&acc)[2][CH],
                                           float (&creg)[2][CH],
                                           ushort* __restrict__ hbl,  // layer base in hb flat
                                           int lane, int ct0) {
    const int l15 = lane & 15, q = lane >> 4;
#pragma unroll
    for (int nt = 0; nt < 2; ++nt) {
#pragma unroll
        for (int mt = 0; mt < CH; ++mt) {
            const int u = (ct0 + mt) * 4 + q;
            const int n = nt * 16 + l15;
            f32x4 z = acc[nt][mt];
            float iv = sigmoid_fast(z[0]);
            float fv = sigmoid_fast(z[1]);
            float gv = tanh_fast(z[2]);
            float ov = sigmoid_fast(z[3]);
            float c = fv * creg[nt][mt] + iv * gv;
            creg[nt][mt] = c;
            hbl[n * HS + u] = f2bf(ov * tanh_fast(c));
        }
    }
}

// direct global -> VGPR weight fragment load (5 tiles, 16B/lane each)
__device__ __forceinline__ void load_frags(s16x8 (&f)[CH],
                                           const ushort* __restrict__ pkl, uint go) {
    const ushort* gp = pkl + go;
#pragma unroll
    for (int mt = 0; mt < CH; ++mt)
        f[mt] = *(const s16x8*)(gp + mt * 512);
}

__device__ __forceinline__ void slot_mfma(s16x8 (&f)[CH], f32x4 (&acc)[2][CH],
                                          const ushort* hbp) {
    s16x8 bh0 = *(const s16x8*)hbp;
    s16x8 bh1 = *(const s16x8*)(hbp + 16 * HS);
#pragma unroll
    for (int mt = 0; mt < CH; ++mt) {
        acc[0][mt] = __builtin_amdgcn_mfma_f32_16x16x32_bf16(f[mt], bh0, acc[0][mt], 0, 0, 0);
        acc[1][mt] = __builtin_amdgcn_mfma_f32_16x16x32_bf16(f[mt], bh1, acc[1][mt], 0, 0, 0);
    }
}

// One region of the 35-slot stream. PAR = buffer parity of slot s0
// (stream invariant: stream slot n lives in buffer n&1; prefetch distance 2
//  refills the buffer just consumed with stream slot n+2 via gTab[s+2 mod 35]).
// Fully unrolled so fA/fB selection is compile-time (no scratch).
template<int PAR, int L>
__device__ __forceinline__ void run_region(const int s0,
        s16x8 (&fA)[CH], s16x8 (&fB)[CH], f32x4 (&acc)[2][CH],
        const ushort* __restrict__ pkl,
        const uint* gT, const uint* bhT,
        const ushort* hbflat, const int bhbase) {
#pragma unroll
    for (int i = 0; i < L; ++i) {
        const int s = s0 + i;                  // compile-time
        int gi = s + 2; if (gi >= 35) gi -= 35; // compile-time
        const ushort* hbp = hbflat + bhT[s] + bhbase;
        const uint go = gT[gi];
        if (((PAR + i) & 1) == 0) {
            slot_mfma(fA, acc, hbp);
            load_frags(fA, pkl, go);
        } else {
            slot_mfma(fB, acc, hbp);
            load_frags(fB, pkl, go);
        }
    }
}

// R1-R3 spill root cause: with only 57.8 KB LDS the backend sees a 2-WG/CU
// occupancy target and caps VGPRs at 84, spilling ~40 regs/step (2.78 GB
// scratch traffic), ignoring waves_per_eu. The 100 KB `stage` ballast below
// restores a 160 KB LDS footprint -> backend knows 1 WG/CU (grid=256=#CUs
// anyway, so zero runtime cost) -> VGPR budget 512/3 = 168 -> demand ~140
// fits with no spill.
__global__ void __launch_bounds__(THREADS)
__attribute__((amdgpu_waves_per_eu(3, 3)))
lstm3_mfma(const float* __restrict__ x,
           const float* __restrict__ W0, const float* __restrict__ b0,
           const float* __restrict__ b1, const float* __restrict__ b2,
           const float* __restrict__ Wfc, const float* __restrict__ bfc,
           const ushort* __restrict__ packed,
           float* __restrict__ out) {
    __shared__ ushort hb[3][BT][HS];        // h state, bf16 (44.5 KB)
    __shared__ ushort stage[10][2][SBUF];   // BALLAST (100 KB) -- see note above
    __shared__ ushort pbwb[4][NP];          // permuted b0,b1,b2,W0 as bf16 (6.4 KB)
    __shared__ ushort xTs[Tlen][BT];        // x transposed, bf16 (6.4 KB)
    __shared__ uint   gTab[35];             // rotated weight-chunk offsets (ushorts)
    __shared__ uint   bhTab[35];            // matching h-operand offsets (ushorts)

    const int tid = threadIdx.x;
    const int wave = tid >> 6, lane = tid & 63;
    const int l15 = lane & 15, q = lane >> 4;
    const int ct0 = wave * CH;
    const int bx = blockIdx.x;
    const int bbase = bx * BT;

    // keep the ballast allocation alive (volatile store cannot be DCE'd)
    if (tid == 0) *(volatile ushort*)&stage[0][0][0] = 0;

    for (int i = tid; i < 3 * BT * HS; i += THREADS) ((ushort*)hb)[i] = 0;
    for (int i = tid; i < NP; i += THREADS) {
        int nc = (i & 3) * Hdim + (i >> 2);   // permuted col -> src col
        pbwb[0][i] = f2bf(b0[nc]); pbwb[1][i] = f2bf(b1[nc]);
        pbwb[2][i] = f2bf(b2[nc]); pbwb[3][i] = f2bf(W0[nc]);
    }
    for (int i = tid; i < BT * Tlen; i += THREADS) {
        int m = i / Tlen, tt = i % Tlen;
        xTs[tt][m] = f2bf(x[(size_t)(bbase + m) * Tlen + tt]);
    }
    // per-WG rotated chunk tables: slot s in [0,35) -> weight offset + h offset
    if (tid < 35) {
        int s = tid; uint goff, bhoff;
        if (s < 7) {                       // layer0: U0, B=h0
            int c = (s + bx) % 7;
            goff = 0u * MATSZ + c * CHSTR;           bhoff = 0u * BT * HS + c * 32;
        } else if (s < 21) {               // layer1: U1 (B=h1) then W1 (B=h0new), rotated
            int c = (s - 7 + bx) % 14;
            if (c < 7) { goff = 2u * MATSZ + c * CHSTR;       bhoff = 1u * BT * HS + c * 32; }
            else       { goff = 1u * MATSZ + (c - 7) * CHSTR; bhoff = 0u * BT * HS + (c - 7) * 32; }
        } else {                           // layer2: U2 (B=h2) then W2 (B=h1new), rotated
            int c = (s - 21 + bx * 5) % 14;
            if (c < 7) { goff = 4u * MATSZ + c * CHSTR;       bhoff = 2u * BT * HS + c * 32; }
            else       { goff = 3u * MATSZ + (c - 7) * CHSTR; bhoff = 1u * BT * HS + (c - 7) * 32; }
        }
        gTab[s] = goff; bhTab[s] = bhoff;
    }
    __syncthreads();

    float creg[3][2][CH];
#pragma unroll
    for (int l = 0; l < 3; ++l)
#pragma unroll
        for (int nt = 0; nt < 2; ++nt)
#pragma unroll
            for (int mt = 0; mt < CH; ++mt) creg[l][nt][mt] = 0.0f;

    // per-lane base into packed weights: wave tile offset + lane 16B slice
    const ushort* pkl = packed + ct0 * 512 + lane * 8;
    ushort* hbflat = &hb[0][0][0];
    const int bhbase = l15 * HS + q * 8;

    // prologue: prefetch stream slots 0 (->fA) and 1 (->fB); distance-2 forever
    s16x8 fA[CH], fB[CH];
    load_frags(fA, pkl, gTab[0]);
    load_frags(fB, pkl, gTab[1]);

    for (int t = 0; t < Tlen; ++t) {
        f32x4 acc[2][CH];

        // ---- layer 0 acc init: b0 + W0^T x_t (bf16 LDS constants) ----
        const float xn0 = bf2f(xTs[t][l15]);
        const float xn1 = bf2f(xTs[t][16 + l15]);
#pragma unroll
        for (int mt = 0; mt < CH; ++mt) {
            const int row = (ct0 + mt) * 16 + q * 4;
            float bb[4], ww[4];
            unpack4(&pbwb[0][row], bb);
            unpack4(&pbwb[3][row], ww);
#pragma unroll
            for (int r = 0; r < 4; ++r) {
                acc[0][mt][r] = fmaf(xn0, ww[r], bb[r]);
                acc[1][mt][r] = fmaf(xn1, ww[r], bb[r]);
            }
        }

        // ---- region A: slots 0..6 (U0 x h0_old); start parity = t&1 ----
        if ((t & 1) == 0) run_region<0, 7>(0, fA, fB, acc, pkl, gTab, bhTab, hbflat, bhbase);
        else              run_region<1, 7>(0, fA, fB, acc, pkl, gTab, bhTab, hbflat, bhbase);
        wg_barrier();
        gate_phase(acc, creg[0], hbflat + 0 * BT * HS, lane, ct0);  // h0 in place
        wg_barrier();

        // ---- layer 1 acc init ----
#pragma unroll
        for (int mt = 0; mt < CH; ++mt) {
            const int row = (ct0 + mt) * 16 + q * 4;
            float bb[4];
            unpack4(&pbwb[1][row], bb);
#pragma unroll
            for (int r = 0; r < 4; ++r) { acc[0][mt][r] = bb[r]; acc[1][mt][r] = bb[r]; }
        }
        // ---- region B: slots 7..20; start parity = (t+7)&1 = (t&1)^1 ----
        if ((t & 1) == 0) run_region<1, 14>(7, fA, fB, acc, pkl, gTab, bhTab, hbflat, bhbase);
        else              run_region<0, 14>(7, fA, fB, acc, pkl, gTab, bhTab, hbflat, bhbase);
        wg_barrier();
        gate_phase(acc, creg[1], hbflat + 1 * BT * HS, lane, ct0);  // h1 in place
        wg_barrier();

        // ---- layer 2 acc init ----
#pragma unroll
        for (int mt = 0; mt < CH; ++mt) {
            const int row = (ct0 + mt) * 16 + q * 4;
            float bb[4];
            unpack4(&pbwb[2][row], bb);
#pragma unroll
            for (int r = 0; r < 4; ++r) { acc[0][mt][r] = bb[r]; acc[1][mt][r] = bb[r]; }
        }
        // ---- region C: slots 21..34; start parity = (t+21)&1 = (t&1)^1 ----
        if ((t & 1) == 0) run_region<1, 14>(21, fA, fB, acc, pkl, gTab, bhTab, hbflat, bhbase);
        else              run_region<0, 14>(21, fA, fB, acc, pkl, gTab, bhTab, hbflat, bhbase);
        wg_barrier();
        gate_phase(acc, creg[2], hbflat + 2 * BT * HS, lane, ct0);  // h2 in place
        wg_barrier();
    }
    __syncthreads();   // h2 visibility for dense head

    // ---- dense head: y = tanh(h2 @ Wfc + bfc) ----
    for (int gidx = tid; gidx < BT * 100; gidx += THREADS) {
        int m = gidx / 100;
        int j4 = (gidx % 100) * 4;
        const ushort* h2 = &hb[2][m][0];
        float4 a4 = *(const float4*)(bfc + j4);
        float s0 = a4.x, s1 = a4.y, s2 = a4.z, s3 = a4.w;
        for (int k = 0; k < Hdim; ++k) {
            float hk = bf2f(h2[k]);
            float4 w4 = *(const float4*)(Wfc + (size_t)k * 400 + j4);
            s0 = fmaf(hk, w4.x, s0);
            s1 = fmaf(hk, w4.y, s1);
            s2 = fmaf(hk, w4.z, s2);
            s3 = fmaf(hk, w4.w, s3);
        }
        float4 o4;
        o4.x = tanh_fast(s0); o4.y = tanh_fast(s1);
        o4.z = tanh_fast(s2); o4.w = tanh_fast(s3);
        *(float4*)(out + (size_t)(bbase + m) * 400 + j4) = o4;
    }
}

extern "C" void kernel_launch(void* const* d_in, const int* in_sizes, int n_in,
                              void* d_out, int out_size, void* d_ws, size_t ws_size,
                              hipStream_t stream) {
    const float* x   = (const float*)d_in[0];
    const float* W0  = (const float*)d_in[1];
    const float* U0  = (const float*)d_in[2];
    const float* b0  = (const float*)d_in[3];
    const float* W1  = (const float*)d_in[4];
    const float* U1  = (const float*)d_in[5];
    const float* b1  = (const float*)d_in[6];
    const float* W2  = (const float*)d_in[7];
    const float* U2  = (const float*)d_in[8];
    const float* b2  = (const float*)d_in[9];
    const float* Wfc = (const float*)d_in[10];
    const float* bfc = (const float*)d_in[11];
    float* out = (float*)d_out;
    ushort* packed = (ushort*)d_ws;

    const int B = in_sizes[0] / Tlen;   // 8192
    const int pack_threads = 5 * KB * NT * 64;
    pack_weights<<<(pack_threads + 255) / 256, 256, 0, stream>>>(U0, W1, U1, W2, U2, packed);
    lstm3_mfma<<<B / BT, THREADS, 0, stream>>>(x, W0, b0, b1, b2, Wfc, bfc, packed, out);
}

// Round 6
// 2989.870 us; speedup vs baseline: 1.2477x; 1.2477x over previous
//
#include <hip/hip_runtime.h>

#define Hdim 200
#define NP   800
#define Tlen 100
#define BT   32          // batch rows per WG -> grid = 256 = 1 WG/CU
#define KB   7           // K blocks of 32 (200 -> 224 padded)
#define HS   232         // padded h row stride (ushorts)
#define NT   50          // 800/16 gate-col tiles
#define THREADS 640      // 10 waves x 5 M-tiles each
#define CH   5           // M-tiles per wave
#define CHSTR (NT*64*8)  // ushorts per K-chunk (25600)
#define MATSZ (KB*CHSTR) // 179200 ushorts per packed matrix

// s_waitcnt immediates: vm[3:0]|exp[6:4]|lgkm[11:8]|vm[15:14]
#define WAIT_LGKM0 0xC07F   // lgkmcnt(0)

typedef float f32x4 __attribute__((ext_vector_type(4)));
typedef short s16x8 __attribute__((ext_vector_type(8)));

__device__ __forceinline__ ushort f2bf(float f) {
    unsigned u = __float_as_uint(f);
    return (ushort)((u + 0x7fffu + ((u >> 16) & 1u)) >> 16);   // RTNE
}
__device__ __forceinline__ float bf2f(ushort s) {
    return __uint_as_float(((unsigned)s) << 16);
}
__device__ __forceinline__ float sigmoid_fast(float v) {
    return 1.0f / (1.0f + __expf(-v));
}
__device__ __forceinline__ float tanh_fast(float v) {
    return 2.0f / (1.0f + __expf(-2.0f * v)) - 1.0f;
}
// WG barrier WITHOUT vmcnt drain: LDS visibility needs lgkmcnt(0) only.
// In-flight global loads target wave-private registers -> safe across barrier.
__device__ __forceinline__ void wg_barrier() {
    asm volatile("" ::: "memory");
    __builtin_amdgcn_s_waitcnt(WAIT_LGKM0);
    __builtin_amdgcn_s_barrier();
    asm volatile("" ::: "memory");
}

// ---- pack 5 recurrent matrices [200][800] fp32 -> bf16 fragment layout ----
// order in d_ws: [U0, W1, U1, W2, U2]
__global__ void pack_weights(const float* __restrict__ U0, const float* __restrict__ W1,
                             const float* __restrict__ U1, const float* __restrict__ W2,
                             const float* __restrict__ U2, ushort* __restrict__ dst) {
    int idx = blockIdx.x * blockDim.x + threadIdx.x;
    if (idx >= 5 * KB * NT * 64) return;
    int lane = idx & 63; int rest = idx >> 6;
    int nt = rest % NT; rest /= NT;
    int kb = rest % KB; int mi = rest / KB;
    const float* src = (mi == 0) ? U0 : (mi == 1) ? W1 : (mi == 2) ? U1 : (mi == 3) ? W2 : U2;
    int np = nt * 16 + (lane & 15);
    int ncol = (np & 3) * Hdim + (np >> 2);          // gate*200 + unit
    int k0 = kb * 32 + (lane >> 4) * 8;
    ushort v[8];
#pragma unroll
    for (int j = 0; j < 8; ++j) {
        int k = k0 + j;
        v[j] = (k < Hdim) ? f2bf(src[k * NP + ncol]) : (ushort)0;
    }
    uint4 o;
    o.x = (unsigned)v[0] | ((unsigned)v[1] << 16);
    o.y = (unsigned)v[2] | ((unsigned)v[3] << 16);
    o.z = (unsigned)v[4] | ((unsigned)v[5] << 16);
    o.w = (unsigned)v[6] | ((unsigned)v[7] << 16);
    ((uint4*)dst)[idx] = o;
}

__device__ __forceinline__ void unpack4(const ushort* p, float (&o)[4]) {
    uint2 u = *(const uint2*)p;
    o[0] = bf2f((ushort)(u.x));  o[1] = bf2f((ushort)(u.x >> 16));
    o[2] = bf2f((ushort)(u.y));  o[3] = bf2f((ushort)(u.y >> 16));
}

// lane-local cell update (unchanged)
__device__ __forceinline__ void gate_phase(f32x4 (&acc)[2][CH],
                                           float (&creg)[2][CH],
                                           ushort* __restrict__ hbl,  // layer base in hb flat
                                           int lane, int ct0) {
    const int l15 = lane & 15, q = lane >> 4;
#pragma unroll
    for (int nt = 0; nt < 2; ++nt) {
#pragma unroll
        for (int mt = 0; mt < CH; ++mt) {
            const int u = (ct0 + mt) * 4 + q;
            const int n = nt * 16 + l15;
            f32x4 z = acc[nt][mt];
            float iv = sigmoid_fast(z[0]);
            float fv = sigmoid_fast(z[1]);
            float gv = tanh_fast(z[2]);
            float ov = sigmoid_fast(z[3]);
            float c = fv * creg[nt][mt] + iv * gv;
            creg[nt][mt] = c;
            hbl[n * HS + u] = f2bf(ov * tanh_fast(c));
        }
    }
}

// One run of slots [s0, s1): weights stream global(L2) -> VGPR -> MFMA,
// loaded and consumed in the SAME iteration. No loop-carried frag state, so
// live-across-barrier pressure is just acc+creg+pointers (~85 regs) -- this is
// what the R1-R5 double-buffered variant got wrong (~165 live -> forced spill).
// #pragma unroll 1 keeps the scheduler from hoisting multiple iterations'
// loads (the pressure blow-up path). The compiler's own vmcnt scheduling
// overlaps the 5 loads with the bh ds_reads; remaining L2 latency is hidden
// by 2.5-wave/SIMD TLP.
__device__ __forceinline__ void run_slots(int s0, int s1,
        f32x4 (&acc)[2][CH],
        const ushort* __restrict__ pkl,
        const uint* gT, const uint* bhT,
        const ushort* hbflat, int bhbase) {
#pragma unroll 1
    for (int s = s0; s < s1; ++s) {
        const ushort* gp = pkl + gT[s];
        s16x8 f0 = *(const s16x8*)(gp);
        s16x8 f1 = *(const s16x8*)(gp + 512);
        s16x8 f2 = *(const s16x8*)(gp + 1024);
        s16x8 f3 = *(const s16x8*)(gp + 1536);
        s16x8 f4 = *(const s16x8*)(gp + 2048);
        const ushort* bp = hbflat + bhT[s] + bhbase;
        s16x8 bh0 = *(const s16x8*)bp;
        s16x8 bh1 = *(const s16x8*)(bp + 16 * HS);
        acc[0][0] = __builtin_amdgcn_mfma_f32_16x16x32_bf16(f0, bh0, acc[0][0], 0, 0, 0);
        acc[1][0] = __builtin_amdgcn_mfma_f32_16x16x32_bf16(f0, bh1, acc[1][0], 0, 0, 0);
        acc[0][1] = __builtin_amdgcn_mfma_f32_16x16x32_bf16(f1, bh0, acc[0][1], 0, 0, 0);
        acc[1][1] = __builtin_amdgcn_mfma_f32_16x16x32_bf16(f1, bh1, acc[1][1], 0, 0, 0);
        acc[0][2] = __builtin_amdgcn_mfma_f32_16x16x32_bf16(f2, bh0, acc[0][2], 0, 0, 0);
        acc[1][2] = __builtin_amdgcn_mfma_f32_16x16x32_bf16(f2, bh1, acc[1][2], 0, 0, 0);
        acc[0][3] = __builtin_amdgcn_mfma_f32_16x16x32_bf16(f3, bh0, acc[0][3], 0, 0, 0);
        acc[1][3] = __builtin_amdgcn_mfma_f32_16x16x32_bf16(f3, bh1, acc[1][3], 0, 0, 0);
        acc[0][4] = __builtin_amdgcn_mfma_f32_16x16x32_bf16(f4, bh0, acc[0][4], 0, 0, 0);
        acc[1][4] = __builtin_amdgcn_mfma_f32_16x16x32_bf16(f4, bh1, acc[1][4], 0, 0, 0);
    }
}

__global__ void __launch_bounds__(THREADS)
lstm3_mfma(const float* __restrict__ x,
           const float* __restrict__ W0, const float* __restrict__ b0,
           const float* __restrict__ b1, const float* __restrict__ b2,
           const float* __restrict__ Wfc, const float* __restrict__ bfc,
           const ushort* __restrict__ packed,
           float* __restrict__ out) {
    __shared__ ushort hb[3][BT][HS];        // h state, bf16 (44.5 KB)
    __shared__ ushort pbwb[4][NP];          // permuted b0,b1,b2,W0 as bf16 (6.4 KB)
    __shared__ ushort xTs[Tlen][BT];        // x transposed, bf16 (6.4 KB)
    __shared__ uint   gTab[35];             // rotated weight-chunk offsets (ushorts)
    __shared__ uint   bhTab[35];            // matching h-operand offsets (ushorts)

    const int tid = threadIdx.x;
    const int wave = tid >> 6, lane = tid & 63;
    const int l15 = lane & 15, q = lane >> 4;
    const int ct0 = wave * CH;
    const int bx = blockIdx.x;
    const int bbase = bx * BT;

    for (int i = tid; i < 3 * BT * HS; i += THREADS) ((ushort*)hb)[i] = 0;
    for (int i = tid; i < NP; i += THREADS) {
        int nc = (i & 3) * Hdim + (i >> 2);   // permuted col -> src col
        pbwb[0][i] = f2bf(b0[nc]); pbwb[1][i] = f2bf(b1[nc]);
        pbwb[2][i] = f2bf(b2[nc]); pbwb[3][i] = f2bf(W0[nc]);
    }
    for (int i = tid; i < BT * Tlen; i += THREADS) {
        int m = i / Tlen, tt = i % Tlen;
        xTs[tt][m] = f2bf(x[(size_t)(bbase + m) * Tlen + tt]);
    }
    // per-WG rotated chunk tables: slot s in [0,35) -> weight offset + h offset
    // (identical to the thrice-verified R1-R3 tables)
    if (tid < 35) {
        int s = tid; uint goff, bhoff;
        if (s < 7) {                       // layer0: U0, B=h0
            int c = (s + bx) % 7;
            goff = 0u * MATSZ + c * CHSTR;           bhoff = 0u * BT * HS + c * 32;
        } else if (s < 21) {               // layer1: U1 (B=h1) then W1 (B=h0new), rotated
            int c = (s - 7 + bx) % 14;
            if (c < 7) { goff = 2u * MATSZ + c * CHSTR;       bhoff = 1u * BT * HS + c * 32; }
            else       { goff = 1u * MATSZ + (c - 7) * CHSTR; bhoff = 0u * BT * HS + (c - 7) * 32; }
        } else {                           // layer2: U2 (B=h2) then W2 (B=h1new), rotated
            int c = (s - 21 + bx * 5) % 14;
            if (c < 7) { goff = 4u * MATSZ + c * CHSTR;       bhoff = 2u * BT * HS + c * 32; }
            else       { goff = 3u * MATSZ + (c - 7) * CHSTR; bhoff = 1u * BT * HS + (c - 7) * 32; }
        }
        gTab[s] = goff; bhTab[s] = bhoff;
    }
    __syncthreads();

    float creg[3][2][CH];
#pragma unroll
    for (int l = 0; l < 3; ++l)
#pragma unroll
        for (int nt = 0; nt < 2; ++nt)
#pragma unroll
            for (int mt = 0; mt < CH; ++mt) creg[l][nt][mt] = 0.0f;

    // per-lane base into packed weights: wave tile offset + lane 16B slice
    const ushort* pkl = packed + ct0 * 512 + lane * 8;
    ushort* hbflat = &hb[0][0][0];
    const int bhbase = l15 * HS + q * 8;

    for (int t = 0; t < Tlen; ++t) {
        f32x4 acc[2][CH];

        // ---- layer 0 acc init: b0 + W0^T x_t (bf16 LDS constants) ----
        const float xn0 = bf2f(xTs[t][l15]);
        const float xn1 = bf2f(xTs[t][16 + l15]);
#pragma unroll
        for (int mt = 0; mt < CH; ++mt) {
            const int row = (ct0 + mt) * 16 + q * 4;
            float bb[4], ww[4];
            unpack4(&pbwb[0][row], bb);
            unpack4(&pbwb[3][row], ww);
#pragma unroll
            for (int r = 0; r < 4; ++r) {
                acc[0][mt][r] = fmaf(xn0, ww[r], bb[r]);
                acc[1][mt][r] = fmaf(xn1, ww[r], bb[r]);
            }
        }

        // ---- region A: slots 0..6 (U0 x h0_old) ----
        run_slots(0, 7, acc, pkl, gTab, bhTab, hbflat, bhbase);
        wg_barrier();
        gate_phase(acc, creg[0], hbflat + 0 * BT * HS, lane, ct0);  // h0 in place
        wg_barrier();

        // ---- layer 1 acc init ----
#pragma unroll
        for (int mt = 0; mt < CH; ++mt) {
            const int row = (ct0 + mt) * 16 + q * 4;
            float bb[4];
            unpack4(&pbwb[1][row], bb);
#pragma unroll
            for (int r = 0; r < 4; ++r) { acc[0][mt][r] = bb[r]; acc[1][mt][r] = bb[r]; }
        }
        // ---- region B: slots 7..20 (U1 x h1_old, W1 x h0_new, rotated mix) ----
        run_slots(7, 21, acc, pkl, gTab, bhTab, hbflat, bhbase);
        wg_barrier();
        gate_phase(acc, creg[1], hbflat + 1 * BT * HS, lane, ct0);  // h1 in place
        wg_barrier();

        // ---- layer 2 acc init ----
#pragma unroll
        for (int mt = 0; mt < CH; ++mt) {
            const int row = (ct0 + mt) * 16 + q * 4;
            float bb[4];
            unpack4(&pbwb[2][row], bb);
#pragma unroll
            for (int r = 0; r < 4; ++r) { acc[0][mt][r] = bb[r]; acc[1][mt][r] = bb[r]; }
        }
        // ---- region C: slots 21..34 (U2 x h2_old, W2 x h1_new, rotated mix) ----
        run_slots(21, 35, acc, pkl, gTab, bhTab, hbflat, bhbase);
        wg_barrier();
        gate_phase(acc, creg[2], hbflat + 2 * BT * HS, lane, ct0);  // h2 in place
        wg_barrier();
    }
    __syncthreads();   // h2 visibility for dense head

    // ---- dense head: y = tanh(h2 @ Wfc + bfc) ----
    for (int gidx = tid; gidx < BT * 100; gidx += THREADS) {
        int m = gidx / 100;
        int j4 = (gidx % 100) * 4;
        const ushort* h2 = &hb[2][m][0];
        float4 a4 = *(const float4*)(bfc + j4);
        float s0 = a4.x, s1 = a4.y, s2 = a4.z, s3 = a4.w;
        for (int k = 0; k < Hdim; ++k) {
            float hk = bf2f(h2[k]);
            float4 w4 = *(const float4*)(Wfc + (size_t)k * 400 + j4);
            s0 = fmaf(hk, w4.x, s0);
            s1 = fmaf(hk, w4.y, s1);
            s2 = fmaf(hk, w4.z, s2);
            s3 = fmaf(hk, w4.w, s3);
        }
        float4 o4;
        o4.x = tanh_fast(s0); o4.y = tanh_fast(s1);
        o4.z = tanh_fast(s2); o4.w = tanh_fast(s3);
        *(float4*)(out + (size_t)(bbase + m) * 400 + j4) = o4;
    }
}

extern "C" void kernel_launch(void* const* d_in, const int* in_sizes, int n_in,
                              void* d_out, int out_size, void* d_ws, size_t ws_size,
                              hipStream_t stream) {
    const float* x   = (const float*)d_in[0];
    const float* W0  = (const float*)d_in[1];
    const float* U0  = (const float*)d_in[2];
    const float* b0  = (const float*)d_in[3];
    const float* W1  = (const float*)d_in[4];
    const float* U1  = (const float*)d_in[5];
    const float* b1  = (const float*)d_in[6];
    const float* W2  = (const float*)d_in[7];
    const float* U2  = (const float*)d_in[8];
    const float* b2  = (const float*)d_in[9];
    const float* Wfc = (const float*)d_in[10];
    const float* bfc = (const float*)d_in[11];
    float* out = (float*)d_out;
    ushort* packed = (ushort*)d_ws;

    const int B = in_sizes[0] / Tlen;   // 8192
    const int pack_threads = 5 * KB * NT * 64;
    pack_weights<<<(pack_threads + 255) / 256, 256, 0, stream>>>(U0, W1, U1, W2, U2, packed);
    lstm3_mfma<<<B / BT, THREADS, 0, stream>>>(x, W0, b0, b1, b2, Wfc, bfc, packed, out);
}

// Round 7
// 2869.137 us; speedup vs baseline: 1.3002x; 1.0421x over previous
//
#include <hip/hip_runtime.h>

#define Hdim 200
#define NP   800
#define Tlen 100
#define BT   32          // batch rows per WG -> grid = 256 = 1 WG/CU
#define KB   7           // K blocks of 32 (200 -> 224 padded)
#define HS   232         // padded h row stride (ushorts)
#define NT   50          // 800/16 gate-col tiles
#define THREADS 640      // 10 waves x 5 M-tiles each
#define CH   5           // M-tiles per wave
#define CHSTR (NT*64*8)  // ushorts per K-chunk (25600)
#define MATSZ (KB*CHSTR) // 179200 ushorts per packed matrix
#define SBUF  2560       // ushorts per stage buffer (5 tiles x 512)

// s_waitcnt immediates: vm[3:0]|exp[6:4]|lgkm[11:8]|vm[15:14]
#define WAIT_VM5   0x0F75   // vmcnt(5)
#define WAIT_LGKM0 0xC07F   // lgkmcnt(0)

typedef float f32x4 __attribute__((ext_vector_type(4)));
typedef short s16x8 __attribute__((ext_vector_type(8)));

__device__ __forceinline__ ushort f2bf(float f) {
    unsigned u = __float_as_uint(f);
    return (ushort)((u + 0x7fffu + ((u >> 16) & 1u)) >> 16);   // RTNE
}
__device__ __forceinline__ float bf2f(ushort s) {
    return __uint_as_float(((unsigned)s) << 16);
}
__device__ __forceinline__ float sigmoid_fast(float v) {
    return 1.0f / (1.0f + __expf(-v));
}
__device__ __forceinline__ float tanh_fast(float v) {
    return 2.0f / (1.0f + __expf(-2.0f * v)) - 1.0f;
}
// WG barrier WITHOUT vmcnt drain: LDS visibility needs lgkmcnt(0) only.
// In-flight weight DMAs/loads target wave-private dest -> safe across barrier.
__device__ __forceinline__ void wg_barrier() {
    asm volatile("" ::: "memory");
    __builtin_amdgcn_s_waitcnt(WAIT_LGKM0);
    __builtin_amdgcn_s_barrier();
    asm volatile("" ::: "memory");
}

// ---- pack 5 recurrent matrices [200][800] fp32 -> bf16 fragment layout ----
// order in d_ws: [U0, W1, U1, W2, U2]
__global__ void pack_weights(const float* __restrict__ U0, const float* __restrict__ W1,
                             const float* __restrict__ U1, const float* __restrict__ W2,
                             const float* __restrict__ U2, ushort* __restrict__ dst) {
    int idx = blockIdx.x * blockDim.x + threadIdx.x;
    if (idx >= 5 * KB * NT * 64) return;
    int lane = idx & 63; int rest = idx >> 6;
    int nt = rest % NT; rest /= NT;
    int kb = rest % KB; int mi = rest / KB;
    const float* src = (mi == 0) ? U0 : (mi == 1) ? W1 : (mi == 2) ? U1 : (mi == 3) ? W2 : U2;
    int np = nt * 16 + (lane & 15);
    int ncol = (np & 3) * Hdim + (np >> 2);          // gate*200 + unit
    int k0 = kb * 32 + (lane >> 4) * 8;
    ushort v[8];
#pragma unroll
    for (int j = 0; j < 8; ++j) {
        int k = k0 + j;
        v[j] = (k < Hdim) ? f2bf(src[k * NP + ncol]) : (ushort)0;
    }
    uint4 o;
    o.x = (unsigned)v[0] | ((unsigned)v[1] << 16);
    o.y = (unsigned)v[2] | ((unsigned)v[3] << 16);
    o.z = (unsigned)v[4] | ((unsigned)v[5] << 16);
    o.w = (unsigned)v[6] | ((unsigned)v[7] << 16);
    ((uint4*)dst)[idx] = o;
}

// 5 async DMAs: one K-chunk's 5 fragment tiles -> wave-private LDS buffer.
__device__ __forceinline__ void stage_chunk(const ushort* gp, ushort* dstbuf, int lane) {
#pragma unroll
    for (int mt = 0; mt < CH; ++mt) {
        __builtin_amdgcn_global_load_lds(
            (const __attribute__((address_space(1))) void*)(gp + (size_t)mt * 512 + lane * 8),
            (__attribute__((address_space(3))) void*)(dstbuf + mt * 512),
            16, 0, 0);
    }
}

__device__ __forceinline__ void unpack4(const ushort* p, float (&o)[4]) {
    uint2 u = *(const uint2*)p;
    o[0] = bf2f((ushort)(u.x));  o[1] = bf2f((ushort)(u.x >> 16));
    o[2] = bf2f((ushort)(u.y));  o[3] = bf2f((ushort)(u.y >> 16));
}

// lane-local cell update (unchanged from R0)
__device__ __forceinline__ void gate_phase(f32x4 (&acc)[2][CH],
                                           float (&creg)[2][CH],
                                           ushort* __restrict__ hbl,  // layer base in hb flat
                                           int lane, int ct0) {
    const int l15 = lane & 15, q = lane >> 4;
#pragma unroll
    for (int nt = 0; nt < 2; ++nt) {
#pragma unroll
        for (int mt = 0; mt < CH; ++mt) {
            const int u = (ct0 + mt) * 4 + q;
            const int n = nt * 16 + l15;
            f32x4 z = acc[nt][mt];
            float iv = sigmoid_fast(z[0]);
            float fv = sigmoid_fast(z[1]);
            float gv = tanh_fast(z[2]);
            float ov = sigmoid_fast(z[3]);
            float c = fv * creg[nt][mt] + iv * gv;
            creg[nt][mt] = c;
            hbl[n * HS + u] = f2bf(ov * tanh_fast(c));
        }
    }
}

__device__ __forceinline__ void mfma10(const s16x8 (&f)[CH], f32x4 (&acc)[2][CH],
                                       const ushort* bp) {
    s16x8 bh0 = *(const s16x8*)bp;
    s16x8 bh1 = *(const s16x8*)(bp + 16 * HS);
#pragma unroll
    for (int mt = 0; mt < CH; ++mt) {
        acc[0][mt] = __builtin_amdgcn_mfma_f32_16x16x32_bf16(f[mt], bh0, acc[0][mt], 0, 0, 0);
        acc[1][mt] = __builtin_amdgcn_mfma_f32_16x16x32_bf16(f[mt], bh1, acc[1][mt], 0, 0, 0);
    }
}

// DMA slot (even s): consume the staged buffer, optionally pre-issue the NEXT
// direct slot's 5 global->reg loads (flight ~1 slot), then restage slot
// (s+4)%36 into the same buffer (2-buffer ring: buffer = (s/2)&1, stateless).
// FIFO audit: each direct slot's fd wait (vmcnt(5)) transitively drains every
// restage >=2 pairs old, so the buffer read here is always complete; the
// explicit vmcnt(5) covers the prologue and is a steady-state no-op.
__device__ __forceinline__ void dma_slot(int s, bool issue_next, s16x8 (&fd)[CH],
        f32x4 (&acc)[2][CH], ushort* sl, const ushort* pk, const ushort* pkl,
        const uint* gTab, const uint* bhTab, const ushort* hbflat, int bhbase, int lane) {
    __builtin_amdgcn_s_waitcnt(WAIT_VM5);
    ushort* buf = sl + ((s >> 1) & 1) * SBUF;
    if (issue_next) {                       // weights are time-invariant: no hazard
        const ushort* gp = pkl + gTab[s + 1];
#pragma unroll
        for (int mt = 0; mt < CH; ++mt)
            fd[mt] = *(const s16x8*)(gp + mt * 512);
    }
    s16x8 frag[CH];
#pragma unroll
    for (int mt = 0; mt < CH; ++mt)
        frag[mt] = *(const s16x8*)(buf + mt * 512 + lane * 8);
    mfma10(frag, acc, hbflat + bhTab[s] + bhbase);
    __builtin_amdgcn_s_waitcnt(WAIT_LGKM0);  // WAR: frag reads done before overwrite
    int rs = s + 4; if (rs >= 36) rs -= 36;  // even, <=34: never hits slot 35
    stage_chunk(pk + gTab[rs], buf, lane);
}

// Direct slot (odd s): MFMA straight from the pre-issued fd registers.
// Compiler inserts the precise vmcnt for fd.
__device__ __forceinline__ void dir_slot(int s, const s16x8 (&fd)[CH], f32x4 (&acc)[2][CH],
        const uint* bhTab, const ushort* hbflat, int bhbase) {
    mfma10(fd, acc, hbflat + bhTab[s] + bhbase);
}

// n pairs of {direct(s), dma(s+1)} starting at odd s0. FRESH: the region's
// first direct slot self-loads fd (keeps fd liveness strictly inside the
// region -- no cross-barrier register state, which is what spilled R1-R5).
// Last dma of the region does NOT pre-issue (next region re-loads fresh).
template<bool FRESH>
__device__ __forceinline__ void run_pairs(int s0, int n, s16x8 (&fd)[CH],
        f32x4 (&acc)[2][CH], ushort* sl, const ushort* pk, const ushort* pkl,
        const uint* gTab, const uint* bhTab, const ushort* hbflat, int bhbase, int lane) {
    if (FRESH) {
        const ushort* gp = pkl + gTab[s0];
#pragma unroll
        for (int mt = 0; mt < CH; ++mt)
            fd[mt] = *(const s16x8*)(gp + mt * 512);
    }
#pragma unroll 1
    for (int i = 0; i < n; ++i) {
        int s = s0 + 2 * i;
        dir_slot(s, fd, acc, bhTab, hbflat, bhbase);
        dma_slot(s + 1, i != n - 1, fd, acc, sl, pk, pkl, gTab, bhTab, hbflat, bhbase, lane);
    }
}

__global__ void __launch_bounds__(THREADS)
lstm3_mfma(const float* __restrict__ x,
           const float* __restrict__ W0, const float* __restrict__ b0,
           const float* __restrict__ b1, const float* __restrict__ b2,
           const float* __restrict__ Wfc, const float* __restrict__ bfc,
           const ushort* __restrict__ packed,
           float* __restrict__ out) {
    __shared__ ushort hb[3][BT][HS];        // h state, bf16 (44.5 KB)
    __shared__ ushort stage[10][2][SBUF];   // 2-deep wave-private staging (100 KB)
    __shared__ ushort pbwb[4][NP];          // permuted b0,b1,b2,W0 as bf16 (6.4 KB)
    __shared__ ushort xTs[Tlen][BT];        // x transposed, bf16 (6.4 KB)
    __shared__ uint   gTab[35];             // rotated weight-chunk offsets (ushorts)
    __shared__ uint   bhTab[35];            // matching h-operand offsets (ushorts)

    const int tid = threadIdx.x;
    const int wave = tid >> 6, lane = tid & 63;
    const int l15 = lane & 15, q = lane >> 4;
    const int ct0 = wave * CH;
    const int bx = blockIdx.x;
    const int bbase = bx * BT;

    for (int i = tid; i < 3 * BT * HS; i += THREADS) ((ushort*)hb)[i] = 0;
    for (int i = tid; i < NP; i += THREADS) {
        int nc = (i & 3) * Hdim + (i >> 2);   // permuted col -> src col
        pbwb[0][i] = f2bf(b0[nc]); pbwb[1][i] = f2bf(b1[nc]);
        pbwb[2][i] = f2bf(b2[nc]); pbwb[3][i] = f2bf(W0[nc]);
    }
    for (int i = tid; i < BT * Tlen; i += THREADS) {
        int m = i / Tlen, tt = i % Tlen;
        xTs[tt][m] = f2bf(x[(size_t)(bbase + m) * Tlen + tt]);
    }
    // per-WG rotated chunk tables: slot s in [0,35) -> weight offset + h offset
    // (identical to the verified R0 tables)
    if (tid < 35) {
        int s = tid; uint goff, bhoff;
        if (s < 7) {                       // layer0: U0, B=h0
            int c = (s + bx) % 7;
            goff = 0u * MATSZ + c * CHSTR;           bhoff = 0u * BT * HS + c * 32;
        } else if (s < 21) {               // layer1: U1 (B=h1) then W1 (B=h0new), rotated
            int c = (s - 7 + bx) % 14;
            if (c < 7) { goff = 2u * MATSZ + c * CHSTR;       bhoff = 1u * BT * HS + c * 32; }
            else       { goff = 1u * MATSZ + (c - 7) * CHSTR; bhoff = 0u * BT * HS + (c - 7) * 32; }
        } else {                           // layer2: U2 (B=h2) then W2 (B=h1new), rotated
            int c = (s - 21 + bx * 5) % 14;
            if (c < 7) { goff = 4u * MATSZ + c * CHSTR;       bhoff = 2u * BT * HS + c * 32; }
            else       { goff = 3u * MATSZ + (c - 7) * CHSTR; bhoff = 1u * BT * HS + (c - 7) * 32; }
        }
        gTab[s] = goff; bhTab[s] = bhoff;
    }
    __syncthreads();

    float creg[3][2][CH];
#pragma unroll
    for (int l = 0; l < 3; ++l)
#pragma unroll
        for (int nt = 0; nt < 2; ++nt)
#pragma unroll
            for (int mt = 0; mt < CH; ++mt) creg[l][nt][mt] = 0.0f;

    const ushort* pk  = packed + (size_t)(ct0 * 64) * 8;   // + wave tile offset
    const ushort* pkl = pk + lane * 8;                     // + lane 16B slice
    ushort* sl = &stage[wave][0][0];
    ushort* hbflat = &hb[0][0][0];
    const int bhbase = l15 * HS + q * 8;

    // prologue: stage DMA-ring slots 0 (->B0) and 2 (->B1)
    stage_chunk(pk + gTab[0], sl, lane);
    stage_chunk(pk + gTab[2], sl + SBUF, lane);

    s16x8 fd[CH];   // direct-slot weight registers (region-local liveness)

    for (int t = 0; t < Tlen; ++t) {
        f32x4 acc[2][CH];

        // ---- layer 0 acc init: b0 + W0^T x_t (bf16 LDS constants) ----
        const float xn0 = bf2f(xTs[t][l15]);
        const float xn1 = bf2f(xTs[t][16 + l15]);
#pragma unroll
        for (int mt = 0; mt < CH; ++mt) {
            const int row = (ct0 + mt) * 16 + q * 4;
            float bb[4], ww[4];
            unpack4(&pbwb[0][row], bb);
            unpack4(&pbwb[3][row], ww);
#pragma unroll
            for (int r = 0; r < 4; ++r) {
                acc[0][mt][r] = fmaf(xn0, ww[r], bb[r]);
                acc[1][mt][r] = fmaf(xn1, ww[r], bb[r]);
            }
        }

        // ---- region A: slots 0..6 = D d D d D d D ----
        dma_slot(0, true, fd, acc, sl, pk, pkl, gTab, bhTab, hbflat, bhbase, lane);
        run_pairs<false>(1, 3, fd, acc, sl, pk, pkl, gTab, bhTab, hbflat, bhbase, lane);
        wg_barrier();
        gate_phase(acc, creg[0], hbflat + 0 * BT * HS, lane, ct0);  // h0 in place
        wg_barrier();

        // ---- layer 1 acc init ----
#pragma unroll
        for (int mt = 0; mt < CH; ++mt) {
            const int row = (ct0 + mt) * 16 + q * 4;
            float bb[4];
            unpack4(&pbwb[1][row], bb);
#pragma unroll
            for (int r = 0; r < 4; ++r) { acc[0][mt][r] = bb[r]; acc[1][mt][r] = bb[r]; }
        }
        // ---- region B: slots 7..20 = 7 x {d, D} ----
        run_pairs<true>(7, 7, fd, acc, sl, pk, pkl, gTab, bhTab, hbflat, bhbase, lane);
        wg_barrier();
        gate_phase(acc, creg[1], hbflat + 1 * BT * HS, lane, ct0);  // h1 in place
        wg_barrier();

        // ---- layer 2 acc init ----
#pragma unroll
        for (int mt = 0; mt < CH; ++mt) {
            const int row = (ct0 + mt) * 16 + q * 4;
            float bb[4];
            unpack4(&pbwb[2][row], bb);
#pragma unroll
            for (int r = 0; r < 4; ++r) { acc[0][mt][r] = bb[r]; acc[1][mt][r] = bb[r]; }
        }
        // ---- region C: slots 21..34 = 7 x {d, D} (restages wrap to next step) ----
        run_pairs<true>(21, 7, fd, acc, sl, pk, pkl, gTab, bhTab, hbflat, bhbase, lane);
        wg_barrier();
        gate_phase(acc, creg[2], hbflat + 2 * BT * HS, lane, ct0);  // h2 in place
        wg_barrier();
    }
    __syncthreads();   // full drain (absorbs the 2 wrap DMAs) + h2 visibility

    // ---- dense head: y = tanh(h2 @ Wfc + bfc) ----
    for (int gidx = tid; gidx < BT * 100; gidx += THREADS) {
        int m = gidx / 100;
        int j4 = (gidx % 100) * 4;
        const ushort* h2 = &hb[2][m][0];
        float4 a4 = *(const float4*)(bfc + j4);
        float s0 = a4.x, s1 = a4.y, s2 = a4.z, s3 = a4.w;
        for (int k = 0; k < Hdim; ++k) {
            float hk = bf2f(h2[k]);
            float4 w4 = *(const float4*)(Wfc + (size_t)k * 400 + j4);
            s0 = fmaf(hk, w4.x, s0);
            s1 = fmaf(hk, w4.y, s1);
            s2 = fmaf(hk, w4.z, s2);
            s3 = fmaf(hk, w4.w, s3);
        }
        float4 o4;
        o4.x = tanh_fast(s0); o4.y = tanh_fast(s1);
        o4.z = tanh_fast(s2); o4.w = tanh_fast(s3);
        *(float4*)(out + (size_t)(bbase + m) * 400 + j4) = o4;
    }
}

extern "C" void kernel_launch(void* const* d_in, const int* in_sizes, int n_in,
                              void* d_out, int out_size, void* d_ws, size_t ws_size,
                              hipStream_t stream) {
    const float* x   = (const float*)d_in[0];
    const float* W0  = (const float*)d_in[1];
    const float* U0  = (const float*)d_in[2];
    const float* b0  = (const float*)d_in[3];
    const float* W1  = (const float*)d_in[4];
    const float* U1  = (const float*)d_in[5];
    const float* b1  = (const float*)d_in[6];
    const float* W2  = (const float*)d_in[7];
    const float* U2  = (const float*)d_in[8];
    const float* b2  = (const float*)d_in[9];
    const float* Wfc = (const float*)d_in[10];
    const float* bfc = (const float*)d_in[11];
    float* out = (float*)d_out;
    ushort* packed = (ushort*)d_ws;

    const int B = in_sizes[0] / Tlen;   // 8192
    const int pack_threads = 5 * KB * NT * 64;
    pack_weights<<<(pack_threads + 255) / 256, 256, 0, stream>>>(U0, W1, U1, W2, U2, packed);
    lstm3_mfma<<<B / BT, THREADS, 0, stream>>>(x, W0, b0, b1, b2, Wfc, bfc, packed, out);
}

// Round 8
// 2631.424 us; speedup vs baseline: 1.4176x; 1.0903x over previous
//
#include <hip/hip_runtime.h>

#define Hdim 200
#define NP   800
#define Tlen 100
#define BT   32          // batch rows per WG -> grid = 256 = 1 WG/CU
#define KB   7           // K blocks of 32 (200 -> 224 padded)
#define HS   232         // padded h row stride (ushorts)
#define NT   50          // 800/16 gate-col tiles
#define THREADS 768      // 12 waves = 3/SIMD exactly (R7 lesson: 640 -> {3,3,2,2} = 20% stretch)
#define CHSTR (NT*64*8)  // ushorts per K-chunk (25600)
#define MATSZ (KB*CHSTR) // 179200 ushorts per packed matrix

// s_waitcnt immediates: vm[3:0]|exp[6:4]|lgkm[11:8]|vm[15:14]
#define WAIT_LGKM0 0xC07F   // lgkmcnt(0)

typedef float f32x4 __attribute__((ext_vector_type(4)));
typedef short s16x8 __attribute__((ext_vector_type(8)));

__device__ __forceinline__ ushort f2bf(float f) {
    unsigned u = __float_as_uint(f);
    return (ushort)((u + 0x7fffu + ((u >> 16) & 1u)) >> 16);   // RTNE
}
__device__ __forceinline__ float bf2f(ushort s) {
    return __uint_as_float(((unsigned)s) << 16);
}
__device__ __forceinline__ float sigmoid_fast(float v) {
    return 1.0f / (1.0f + __expf(-v));
}
__device__ __forceinline__ float tanh_fast(float v) {
    return 2.0f / (1.0f + __expf(-2.0f * v)) - 1.0f;
}
// WG barrier WITHOUT vmcnt drain: LDS visibility needs lgkmcnt(0) only.
// Weight DMAs in flight target wave-private buffers -> safe across barrier.
__device__ __forceinline__ void wg_barrier() {
    asm volatile("" ::: "memory");
    __builtin_amdgcn_s_waitcnt(WAIT_LGKM0);
    __builtin_amdgcn_s_barrier();
    asm volatile("" ::: "memory");
}

// ---- pack 5 recurrent matrices [200][800] fp32 -> bf16 fragment layout ----
// order in d_ws: [U0, W1, U1, W2, U2]  (tile layout unchanged from R0)
__global__ void pack_weights(const float* __restrict__ U0, const float* __restrict__ W1,
                             const float* __restrict__ U1, const float* __restrict__ W2,
                             const float* __restrict__ U2, ushort* __restrict__ dst) {
    int idx = blockIdx.x * blockDim.x + threadIdx.x;
    if (idx >= 5 * KB * NT * 64) return;
    int lane = idx & 63; int rest = idx >> 6;
    int nt = rest % NT; rest /= NT;
    int kb = rest % KB; int mi = rest / KB;
    const float* src = (mi == 0) ? U0 : (mi == 1) ? W1 : (mi == 2) ? U1 : (mi == 3) ? W2 : U2;
    int np = nt * 16 + (lane & 15);
    int ncol = (np & 3) * Hdim + (np >> 2);          // gate*200 + unit
    int k0 = kb * 32 + (lane >> 4) * 8;
    ushort v[8];
#pragma unroll
    for (int j = 0; j < 8; ++j) {
        int k = k0 + j;
        v[j] = (k < Hdim) ? f2bf(src[k * NP + ncol]) : (ushort)0;
    }
    uint4 o;
    o.x = (unsigned)v[0] | ((unsigned)v[1] << 16);
    o.y = (unsigned)v[2] | ((unsigned)v[3] << 16);
    o.z = (unsigned)v[4] | ((unsigned)v[5] << 16);
    o.w = (unsigned)v[6] | ((unsigned)v[7] << 16);
    ((uint4*)dst)[idx] = o;
}

// CHW async DMAs: one K-chunk's CHW fragment tiles -> wave-private LDS buffer.
template<int CHW>
__device__ __forceinline__ void stage_chunk(const ushort* gp, ushort* dstbuf, int lane) {
#pragma unroll
    for (int mt = 0; mt < CHW; ++mt) {
        __builtin_amdgcn_global_load_lds(
            (const __attribute__((address_space(1))) void*)(gp + (size_t)mt * 512 + lane * 8),
            (__attribute__((address_space(3))) void*)(dstbuf + mt * 512),
            16, 0, 0);
    }
}

__device__ __forceinline__ void unpack4(const ushort* p, float (&o)[4]) {
    uint2 u = *(const uint2*)p;
    o[0] = bf2f((ushort)(u.x));  o[1] = bf2f((ushort)(u.x >> 16));
    o[2] = bf2f((ushort)(u.y));  o[3] = bf2f((ushort)(u.y >> 16));
}

// lane-local cell update (R0 body, CHW-templated; u = (S_w+mt)*4+q)
template<int CHW>
__device__ __forceinline__ void gate_phase(f32x4 (&acc)[2][CHW],
                                           float (&creg)[2][CHW],
                                           ushort* __restrict__ hbl,
                                           int lane, int S_w) {
    const int l15 = lane & 15, q = lane >> 4;
#pragma unroll
    for (int nt = 0; nt < 2; ++nt) {
#pragma unroll
        for (int mt = 0; mt < CHW; ++mt) {
            const int u = (S_w + mt) * 4 + q;
            const int n = nt * 16 + l15;
            f32x4 z = acc[nt][mt];
            float iv = sigmoid_fast(z[0]);
            float fv = sigmoid_fast(z[1]);
            float gv = tanh_fast(z[2]);
            float ov = sigmoid_fast(z[3]);
            float c = fv * creg[nt][mt] + iv * gv;
            creg[nt][mt] = c;
            hbl[n * HS + u] = f2bf(ov * tanh_fast(c));
        }
    }
}

// One run of slots [s0, s1): identical per-slot body to the verified R0 kernel
// (vmcnt(CHW) wait -> ds_read frags + bh -> 2*CHW MFMA -> lgkmcnt(0) -> restage).
template<int CHW>
__device__ __forceinline__ void run_slots(int s0, int s1, int t,
        ushort* __restrict__ sl, f32x4 (&acc)[2][CHW],
        const ushort* __restrict__ pk, const uint* gTab, const uint* bhTab,
        const ushort* hbflat, int bhbase, int lane, int& isl) {
#pragma unroll 1
    for (int s = s0; s < s1; ++s) {
        __builtin_amdgcn_s_waitcnt(0x0F70 | CHW);   // vmcnt(CHW): other buffer in flight
        ushort* buf = sl + ((t + s) & 1) * (CHW * 512);
        s16x8 frag[CHW];
#pragma unroll
        for (int mt = 0; mt < CHW; ++mt)
            frag[mt] = *(const s16x8*)(buf + mt * 512 + lane * 8);
        const ushort* bp = hbflat + bhTab[s] + bhbase;
        s16x8 bh0 = *(const s16x8*)bp;
        s16x8 bh1 = *(const s16x8*)(bp + 16 * HS);
#pragma unroll
        for (int mt = 0; mt < CHW; ++mt) {
            acc[0][mt] = __builtin_amdgcn_mfma_f32_16x16x32_bf16(frag[mt], bh0, acc[0][mt], 0, 0, 0);
            acc[1][mt] = __builtin_amdgcn_mfma_f32_16x16x32_bf16(frag[mt], bh1, acc[1][mt], 0, 0, 0);
        }
        __builtin_amdgcn_s_waitcnt(WAIT_LGKM0);  // WAR: frag reads done before restage
        stage_chunk<CHW>(pk + gTab[isl], buf, lane);
        isl = (isl == 34) ? 0 : isl + 1;
    }
}

// Full 100-step loop, templated on the wave's tile count. Both instantiations
// execute an identical barrier sequence (6/step), so divergent wave-uniform
// dispatch below is barrier-safe.
template<int CHW>
__device__ __forceinline__ void time_loop(const int S_w, const int lane,
        const int bhbase, ushort* __restrict__ sl, const ushort* __restrict__ pk,
        const uint* gTab, const uint* bhTab, ushort* __restrict__ hbflat,
        const ushort (&pbwb)[4][NP], const ushort (&xTs)[Tlen][BT]) {
    const int l15 = lane & 15, q = lane >> 4;

    float creg[3][2][CHW];
#pragma unroll
    for (int l = 0; l < 3; ++l)
#pragma unroll
        for (int nt = 0; nt < 2; ++nt)
#pragma unroll
            for (int mt = 0; mt < CHW; ++mt) creg[l][nt][mt] = 0.0f;

    // prologue: issue slots 0,1 (parities 0,1); steady 2*CHW DMAs in flight
    stage_chunk<CHW>(pk + gTab[0], sl, lane);
    stage_chunk<CHW>(pk + gTab[1], sl + CHW * 512, lane);
    int isl = 2;

    for (int t = 0; t < Tlen; ++t) {
        f32x4 acc[2][CHW];

        // ---- layer 0 acc init: b0 + W0^T x_t (bf16 LDS constants) ----
        const float xn0 = bf2f(xTs[t][l15]);
        const float xn1 = bf2f(xTs[t][16 + l15]);
#pragma unroll
        for (int mt = 0; mt < CHW; ++mt) {
            const int row = (S_w + mt) * 16 + q * 4;
            float bb[4], ww[4];
            unpack4(&pbwb[0][row], bb);
            unpack4(&pbwb[3][row], ww);
#pragma unroll
            for (int r = 0; r < 4; ++r) {
                acc[0][mt][r] = fmaf(xn0, ww[r], bb[r]);
                acc[1][mt][r] = fmaf(xn1, ww[r], bb[r]);
            }
        }

        // ---- region A: slots 0..6 (U0 x h0_old) ----
        run_slots<CHW>(0, 7, t, sl, acc, pk, gTab, bhTab, hbflat, bhbase, lane, isl);
        wg_barrier();
        gate_phase<CHW>(acc, creg[0], hbflat + 0 * BT * HS, lane, S_w);
        wg_barrier();

        // ---- layer 1 acc init ----
#pragma unroll
        for (int mt = 0; mt < CHW; ++mt) {
            const int row = (S_w + mt) * 16 + q * 4;
            float bb[4];
            unpack4(&pbwb[1][row], bb);
#pragma unroll
            for (int r = 0; r < 4; ++r) { acc[0][mt][r] = bb[r]; acc[1][mt][r] = bb[r]; }
        }
        // ---- region B: slots 7..20 (U1 x h1_old, W1 x h0_new, rotated mix) ----
        run_slots<CHW>(7, 21, t, sl, acc, pk, gTab, bhTab, hbflat, bhbase, lane, isl);
        wg_barrier();
        gate_phase<CHW>(acc, creg[1], hbflat + 1 * BT * HS, lane, S_w);
        wg_barrier();

        // ---- layer 2 acc init ----
#pragma unroll
        for (int mt = 0; mt < CHW; ++mt) {
            const int row = (S_w + mt) * 16 + q * 4;
            float bb[4];
            unpack4(&pbwb[2][row], bb);
#pragma unroll
            for (int r = 0; r < 4; ++r) { acc[0][mt][r] = bb[r]; acc[1][mt][r] = bb[r]; }
        }
        // ---- region C: slots 21..34 (U2 x h2_old, W2 x h1_new, rotated mix) ----
        run_slots<CHW>(21, 35, t, sl, acc, pk, gTab, bhTab, hbflat, bhbase, lane, isl);
        wg_barrier();
        gate_phase<CHW>(acc, creg[2], hbflat + 2 * BT * HS, lane, S_w);
        wg_barrier();
    }
}

__global__ void __launch_bounds__(THREADS)
lstm3_mfma(const float* __restrict__ x,
           const float* __restrict__ W0, const float* __restrict__ b0,
           const float* __restrict__ b1, const float* __restrict__ b2,
           const float* __restrict__ Wfc, const float* __restrict__ bfc,
           const ushort* __restrict__ packed,
           float* __restrict__ out) {
    __shared__ ushort hb[3][BT][HS];        // h state, bf16 (44.5 KB)
    __shared__ ushort stage[NT * 1024];     // per-wave 2-deep staging, packed (100 KB)
    __shared__ ushort pbwb[4][NP];          // permuted b0,b1,b2,W0 as bf16 (6.4 KB)
    __shared__ ushort xTs[Tlen][BT];        // x transposed, bf16 (6.4 KB)
    __shared__ uint   gTab[35];             // rotated weight-chunk offsets (ushorts)
    __shared__ uint   bhTab[35];            // matching h-operand offsets (ushorts)

    const int tid = threadIdx.x;
    const int wave = tid >> 6, lane = tid & 63;
    const int bx = blockIdx.x;
    const int bbase = bx * BT;

    for (int i = tid; i < 3 * BT * HS; i += THREADS) ((ushort*)hb)[i] = 0;
    for (int i = tid; i < NP; i += THREADS) {
        int nc = (i & 3) * Hdim + (i >> 2);   // permuted col -> src col
        pbwb[0][i] = f2bf(b0[nc]); pbwb[1][i] = f2bf(b1[nc]);
        pbwb[2][i] = f2bf(b2[nc]); pbwb[3][i] = f2bf(W0[nc]);
    }
    for (int i = tid; i < BT * Tlen; i += THREADS) {
        int m = i / Tlen, tt = i % Tlen;
        xTs[tt][m] = f2bf(x[(size_t)(bbase + m) * Tlen + tt]);
    }
    // per-WG rotated chunk tables: slot s in [0,35) -> weight offset + h offset
    // (identical to the verified R0 tables)
    if (tid < 35) {
        int s = tid; uint goff, bhoff;
        if (s < 7) {                       // layer0: U0, B=h0
            int c = (s + bx) % 7;
            goff = 0u * MATSZ + c * CHSTR;           bhoff = 0u * BT * HS + c * 32;
        } else if (s < 21) {               // layer1: U1 (B=h1) then W1 (B=h0new), rotated
            int c = (s - 7 + bx) % 14;
            if (c < 7) { goff = 2u * MATSZ + c * CHSTR;       bhoff = 1u * BT * HS + c * 32; }
            else       { goff = 1u * MATSZ + (c - 7) * CHSTR; bhoff = 0u * BT * HS + (c - 7) * 32; }
        } else {                           // layer2: U2 (B=h2) then W2 (B=h1new), rotated
            int c = (s - 21 + bx * 5) % 14;
            if (c < 7) { goff = 4u * MATSZ + c * CHSTR;       bhoff = 2u * BT * HS + c * 32; }
            else       { goff = 3u * MATSZ + (c - 7) * CHSTR; bhoff = 1u * BT * HS + (c - 7) * 32; }
        }
        gTab[s] = goff; bhTab[s] = bhoff;
    }
    __syncthreads();

    // Tile split: waves 0,1 own 5 tiles; waves 2..11 own 4 (total 50).
    // Round-robin wave->SIMD puts the 5-tile waves on SIMD0/SIMD1:
    // per-SIMD tiles {13,13,12,12} -> 4% imbalance (vs 640-thread 15/10 = 20%).
    const int S_w = (wave < 2) ? wave * 5 : 10 + (wave - 2) * 4;
    const ushort* pk = packed + (size_t)S_w * 512;   // wave's first tile
    ushort* sl = &stage[S_w * 1024];                 // 2 x CHW x 512 ushorts
    ushort* hbflat = &hb[0][0][0];
    const int bhbase = (lane & 15) * HS + (lane >> 4) * 8;

    if (wave < 2) time_loop<5>(S_w, lane, bhbase, sl, pk, gTab, bhTab, hbflat, pbwb, xTs);
    else          time_loop<4>(S_w, lane, bhbase, sl, pk, gTab, bhTab, hbflat, pbwb, xTs);

    __syncthreads();   // full drain (absorbs wrap DMAs) + h2 visibility

    // ---- dense head: y = tanh(h2 @ Wfc + bfc) ----
    for (int gidx = tid; gidx < BT * 100; gidx += THREADS) {
        int m = gidx / 100;
        int j4 = (gidx % 100) * 4;
        const ushort* h2 = &hb[2][m][0];
        float4 a4 = *(const float4*)(bfc + j4);
        float s0 = a4.x, s1 = a4.y, s2 = a4.z, s3 = a4.w;
        for (int k = 0; k < Hdim; ++k) {
            float hk = bf2f(h2[k]);
            float4 w4 = *(const float4*)(Wfc + (size_t)k * 400 + j4);
            s0 = fmaf(hk, w4.x, s0);
            s1 = fmaf(hk, w4.y, s1);
            s2 = fmaf(hk, w4.z, s2);
            s3 = fmaf(hk, w4.w, s3);
        }
        float4 o4;
        o4.x = tanh_fast(s0); o4.y = tanh_fast(s1);
        o4.z = tanh_fast(s2); o4.w = tanh_fast(s3);
        *(float4*)(out + (size_t)(bbase + m) * 400 + j4) = o4;
    }
}

extern "C" void kernel_launch(void* const* d_in, const int* in_sizes, int n_in,
                              void* d_out, int out_size, void* d_ws, size_t ws_size,
                              hipStream_t stream) {
    const float* x   = (const float*)d_in[0];
    const float* W0  = (const float*)d_in[1];
    const float* U0  = (const float*)d_in[2];
    const float* b0  = (const float*)d_in[3];
    const float* W1  = (const float*)d_in[4];
    const float* U1  = (const float*)d_in[5];
    const float* b1  = (const float*)d_in[6];
    const float* W2  = (const float*)d_in[7];
    const float* U2  = (const float*)d_in[8];
    const float* b2  = (const float*)d_in[9];
    const float* Wfc = (const float*)d_in[10];
    const float* bfc = (const float*)d_in[11];
    float* out = (float*)d_out;
    ushort* packed = (ushort*)d_ws;

    const int B = in_sizes[0] / Tlen;   // 8192
    const int pack_threads = 5 * KB * NT * 64;
    pack_weights<<<(pack_threads + 255) / 256, 256, 0, stream>>>(U0, W1, U1, W2, U2, packed);
    lstm3_mfma<<<B / BT, THREADS, 0, stream>>>(x, W0, b0, b1, b2, Wfc, bfc, packed, out);
}